// Round 1
// baseline (1007.862 us; speedup 1.0000x reference)
//
#include <hip/hip_runtime.h>
#include <hip/hip_bf16.h>
#include <cstdint>
#include <cstddef>

#define NHEADS 16
#define HDIM   88
#define SEQLEN 577
#define NBATCH 32
#define DMODEL 1408
#define MROWS  (NBATCH * SEQLEN)   /* 18464 */
#define MTILES 145
#define MPAD   (MTILES * 128)      /* 18560 */
#define SP     592                 /* padded seq rows per (b,h) */
#define DP     96                  /* padded head dim */
#define NFREQ  44
#define NBH    (NBATCH * NHEADS)   /* 512 */

typedef __attribute__((ext_vector_type(8))) short short8;
typedef __attribute__((ext_vector_type(4))) float floatx4;

__device__ __forceinline__ unsigned short f2bf(float f) {
    union { float f; unsigned u; } v; v.f = f;
    unsigned u = v.u;
    u += 0x7fffu + ((u >> 16) & 1u);          // RNE
    return (unsigned short)(u >> 16);
}

__device__ __forceinline__ void gload_lds16(const void* g, void* lds) {
    __builtin_amdgcn_global_load_lds(
        (__attribute__((address_space(1))) unsigned int*)(void*)(g ? (void*)g : (void*)g),
        (__attribute__((address_space(3))) unsigned int*)lds, 16, 0, 0);
}

// ---------------- rope table: cos/sin [SEQLEN][NFREQ] ----------------
__global__ void l4v_rope_table(float* __restrict__ cos_t, float* __restrict__ sin_t) {
    int idx = blockIdx.x * blockDim.x + threadIdx.x;
    if (idx >= SEQLEN * NFREQ) return;
    int s = idx / NFREQ, j = idx % NFREQ;
    float ang = 0.0f;
    if (s != SEQLEN - 1) {
        int coord = (j < 22) ? (s % 24) : (s / 24);
        int i = (j < 22) ? j : j - 22;
        float rf = __expf(-(2.0f * (float)i / 44.0f) * 9.21034037197618f); // ln(10000)
        ang = (float)(coord + 1) * rf;
    }
    cos_t[idx] = cosf(ang);
    sin_t[idx] = sinf(ang);
}

// ---------------- fp32 -> bf16 convert ----------------
__global__ void l4v_cvt_bf16(const float* __restrict__ in, unsigned short* __restrict__ out, int n) {
    int i = (blockIdx.x * blockDim.x + threadIdx.x) * 4;
    if (i + 3 < n) {
        float4 f = *(const float4*)(in + i);
        ushort4 o;
        o.x = f2bf(f.x); o.y = f2bf(f.y); o.z = f2bf(f.z); o.w = f2bf(f.w);
        *(ushort4*)(out + i) = o;
    } else {
        for (; i < n; i++) out[i] = f2bf(in[i]);
    }
}

// ---------------- 128x128 bf16 MFMA GEMM, C = A @ Bw^T + bias ----------------
// A [MPAD][DMODEL] bf16 row-major, Bw [DMODEL][DMODEL] bf16 row-major (row=n, k contig)
// mode 0: Q (rope, store bf16 [bh][SP][DP]); 1: K (same); 2: V (no rope, same);
// mode 3: out-proj (store fp32 to d_out [MROWS][DMODEL])
__global__ __launch_bounds__(256, 2)
void l4v_gemm128(const unsigned short* __restrict__ A,
                 const unsigned short* __restrict__ Bw,
                 const float* __restrict__ bias,
                 const float* __restrict__ cos_t,
                 const float* __restrict__ sin_t,
                 unsigned short* __restrict__ out_bf,
                 float* __restrict__ out_f32,
                 int mode)
{
    __shared__ __align__(16) unsigned short a_sm[128 * 32];
    __shared__ __align__(16) unsigned short b_sm[128 * 32];

    const int tid  = threadIdx.x;
    const int lane = tid & 63;
    const int w    = tid >> 6;
    const int quad = lane >> 4;
    const int c    = lane & 15;
    const int wr   = w >> 1;
    const int wc   = w & 1;
    const int m0   = blockIdx.y * 128;
    const int n0   = blockIdx.x * 128;

    floatx4 acc[4][4];
#pragma unroll
    for (int i = 0; i < 4; i++)
#pragma unroll
        for (int j = 0; j < 4; j++) acc[i][j] = (floatx4)0.0f;

    const int chunk0 = w * 128 + lane;
    const int chunk1 = w * 128 + 64 + lane;
    const int r0 = chunk0 >> 2, ch0 = chunk0 & 3;
    const int r1 = chunk1 >> 2, ch1 = chunk1 & 3;
    const unsigned short* Ab = A  + (size_t)m0 * DMODEL;
    const unsigned short* Bb = Bw + (size_t)n0 * DMODEL;

    for (int k0 = 0; k0 < DMODEL; k0 += 32) {
        gload_lds16(Ab + (size_t)r0 * DMODEL + k0 + ch0 * 8, a_sm + (w * 128) * 8);
        gload_lds16(Ab + (size_t)r1 * DMODEL + k0 + ch1 * 8, a_sm + (w * 128 + 64) * 8);
        gload_lds16(Bb + (size_t)r0 * DMODEL + k0 + ch0 * 8, b_sm + (w * 128) * 8);
        gload_lds16(Bb + (size_t)r1 * DMODEL + k0 + ch1 * 8, b_sm + (w * 128 + 64) * 8);
        __syncthreads();
        short8 af[4], bfr[4];
#pragma unroll
        for (int mt = 0; mt < 4; mt++)
            af[mt] = *(const short8*)(a_sm + (wr * 64 + mt * 16 + c) * 32 + quad * 8);
#pragma unroll
        for (int nt = 0; nt < 4; nt++)
            bfr[nt] = *(const short8*)(b_sm + (wc * 64 + nt * 16 + c) * 32 + quad * 8);
#pragma unroll
        for (int mt = 0; mt < 4; mt++)
#pragma unroll
            for (int nt = 0; nt < 4; nt++)
                acc[mt][nt] = __builtin_amdgcn_mfma_f32_16x16x32_bf16(af[mt], bfr[nt], acc[mt][nt], 0, 0, 0);
        __syncthreads();
    }

    // ---------------- epilogue ----------------
    if (mode == 3) {
#pragma unroll
        for (int mt = 0; mt < 4; mt++) {
            int mbase = m0 + wr * 64 + mt * 16 + quad * 4;
#pragma unroll
            for (int nt = 0; nt < 4; nt++) {
                int n = n0 + wc * 64 + nt * 16 + c;
                float bi = bias[n];
#pragma unroll
                for (int r = 0; r < 4; r++) {
                    int m = mbase + r;
                    if (m < MROWS) out_f32[(size_t)m * DMODEL + n] = acc[mt][nt][r] + bi;
                }
            }
        }
        return;
    }

    const bool rope = (mode < 2);
#pragma unroll
    for (int mt = 0; mt < 4; mt++) {
        int mbase = m0 + wr * 64 + mt * 16 + quad * 4;
#pragma unroll
        for (int nt = 0; nt < 4; nt++) {
            int n = n0 + wc * 64 + nt * 16 + c;
            float bi = bias[n];
            int h = n / HDIM, d = n % HDIM, j = d >> 1;
#pragma unroll
            for (int r = 0; r < 4; r++) {
                int m = mbase + r;
                int s = m % SEQLEN;
                int b = m / SEQLEN;
                float v = acc[mt][nt][r] + bi;
                float outv = v;
                if (rope) {
                    float pv = __shfl_xor(v, 1);   // partner element of the complex pair
                    float cs = cos_t[s * NFREQ + j];
                    float sn = sin_t[s * NFREQ + j];
                    outv = ((d & 1) == 0) ? (v * cs - pv * sn) : (pv * sn + v * cs);
                }
                if (m < MROWS)
                    out_bf[((size_t)(b * NHEADS + h) * SP + s) * DP + d] = f2bf(outv);
            }
        }
    }
}

// ---------------- flash attention ----------------
// grid (10, 512): x = q-tile (64 rows), y = (b*16+h). block = 256 (4 waves, 16 q-rows each)
__global__ __launch_bounds__(256, 2)
void l4v_attn(const unsigned short* __restrict__ Q,
              const unsigned short* __restrict__ K,
              const unsigned short* __restrict__ V,
              unsigned short* __restrict__ Obuf)
{
    __shared__ __align__(16) unsigned short k_sm[64 * DP];
    __shared__ __align__(16) unsigned short v_sm[64 * DP];
    __shared__ __align__(16) unsigned short p_sm[4][16 * 64];

    const int tid  = threadIdx.x;
    const int lane = tid & 63;
    const int w    = tid >> 6;
    const int quad = lane >> 4;
    const int c    = lane & 15;
    const int qt   = blockIdx.x;
    const int bh   = blockIdx.y;
    const size_t base = (size_t)bh * SP * DP;

    // Q fragments (A-operand): row = qt*64 + w*16 + c, k = ks*32 + quad*8 + j
    short8 aq[3];
    {
        int qrow = qt * 64 + w * 16 + c;
        if (qrow > SP - 1) qrow = SP - 1;
#pragma unroll
        for (int ks = 0; ks < 3; ks++)
            aq[ks] = *(const short8*)(Q + base + (size_t)qrow * DP + ks * 32 + quad * 8);
    }

    float m_run[4], l_run[4];
    floatx4 o_acc[6];
#pragma unroll
    for (int r = 0; r < 4; r++) { m_run[r] = -INFINITY; l_run[r] = 0.0f; }
#pragma unroll
    for (int i = 0; i < 6; i++) o_acc[i] = (floatx4)0.0f;

    const float sl2e = 0.10660035817780522f * 1.4426950408889634f; // (1/sqrt(88))*log2(e)

    for (int kt = 0; kt < 10; kt++) {
        // stage K,V tiles [64][DP] via global_load_lds
#pragma unroll
        for (int i = 0; i < 3; i++) {
            int chnk = w * 192 + i * 64 + lane;
            int row = chnk / 12, ch = chnk % 12;
            int krow = kt * 64 + row;
            if (krow > SP - 1) krow = SP - 1;
            gload_lds16(K + base + (size_t)krow * DP + ch * 8, k_sm + (w * 192 + i * 64) * 8);
            gload_lds16(V + base + (size_t)krow * DP + ch * 8, v_sm + (w * 192 + i * 64) * 8);
        }
        __syncthreads();

        // scores: 4 s_k sub-tiles x 3 k-steps
        floatx4 sc[4];
#pragma unroll
        for (int nt = 0; nt < 4; nt++) {
            sc[nt] = (floatx4)0.0f;
#pragma unroll
            for (int ks = 0; ks < 3; ks++) {
                short8 bk = *(const short8*)(k_sm + (nt * 16 + c) * DP + ks * 32 + quad * 8);
                sc[nt] = __builtin_amdgcn_mfma_f32_16x16x32_bf16(aq[ks], bk, sc[nt], 0, 0, 0);
            }
        }

        // masked, scaled (in log2 units)
        float t[4][4];
#pragma unroll
        for (int nt = 0; nt < 4; nt++) {
            int skcol = kt * 64 + nt * 16 + c;
            bool valid = (skcol < SEQLEN);
#pragma unroll
            for (int r = 0; r < 4; r++)
                t[nt][r] = valid ? sc[nt][r] * sl2e : -INFINITY;
        }

        float mnew[4], alpha[4];
#pragma unroll
        for (int r = 0; r < 4; r++) {
            float v = fmaxf(fmaxf(t[0][r], t[1][r]), fmaxf(t[2][r], t[3][r]));
#pragma unroll
            for (int off = 1; off < 16; off <<= 1) v = fmaxf(v, __shfl_xor(v, off));
            mnew[r] = fmaxf(m_run[r], v);
            alpha[r] = exp2f(m_run[r] - mnew[r]);
            m_run[r] = mnew[r];
        }

        float p[4][4];
#pragma unroll
        for (int nt = 0; nt < 4; nt++)
#pragma unroll
            for (int r = 0; r < 4; r++)
                p[nt][r] = exp2f(t[nt][r] - mnew[r]);

#pragma unroll
        for (int r = 0; r < 4; r++) {
            float sm = p[0][r] + p[1][r] + p[2][r] + p[3][r];
#pragma unroll
            for (int off = 1; off < 16; off <<= 1) sm += __shfl_xor(sm, off);
            l_run[r] = l_run[r] * alpha[r] + sm;
        }

        // P -> LDS (C-layout -> A-layout transpose), wave-private
#pragma unroll
        for (int nt = 0; nt < 4; nt++)
#pragma unroll
            for (int r = 0; r < 4; r++)
                p_sm[w][(quad * 4 + r) * 64 + nt * 16 + c] = f2bf(p[nt][r]);

        // rescale O
#pragma unroll
        for (int i = 0; i < 6; i++)
#pragma unroll
            for (int r = 0; r < 4; r++)
                o_acc[i][r] *= alpha[r];

        // PV: A = P (m = q-row), B = V (k = s_k, n = d)
#pragma unroll
        for (int kp = 0; kp < 2; kp++) {
            short8 ap = *(const short8*)(&p_sm[w][c * 64 + kp * 32 + quad * 8]);
#pragma unroll
            for (int d2 = 0; d2 < 6; d2++) {
                short8 bv;
#pragma unroll
                for (int j = 0; j < 8; j++)
                    bv[j] = (short)v_sm[(kp * 32 + quad * 8 + j) * DP + d2 * 16 + c];
                o_acc[d2] = __builtin_amdgcn_mfma_f32_16x16x32_bf16(ap, bv, o_acc[d2], 0, 0, 0);
            }
        }
        __syncthreads();
    }

    // store: row = b*577 + s_q, col = h*88 + d  (bf16 into attn buffer)
    const int b = bh >> 4, h = bh & 15;
#pragma unroll
    for (int r = 0; r < 4; r++) {
        int sq = qt * 64 + w * 16 + quad * 4 + r;
        float il = 1.0f / l_run[r];
        if (sq < SEQLEN) {
            size_t rowoff = ((size_t)b * SEQLEN + sq) * DMODEL + h * HDIM;
#pragma unroll
            for (int d2 = 0; d2 < 6; d2++) {
                int d = d2 * 16 + c;
                if (d < HDIM) Obuf[rowoff + d] = f2bf(o_acc[d2][r] * il);
            }
        }
    }
}

// ---------------- launcher ----------------
extern "C" void kernel_launch(void* const* d_in, const int* in_sizes, int n_in,
                              void* d_out, int out_size, void* d_ws, size_t ws_size,
                              hipStream_t stream)
{
    const float* hs = (const float*)d_in[0];
    const float* wq = (const float*)d_in[1];
    const float* bq = (const float*)d_in[2];
    const float* wk = (const float*)d_in[3];
    const float* bk = (const float*)d_in[4];
    const float* wv = (const float*)d_in[5];
    const float* bv = (const float*)d_in[6];
    const float* wo = (const float*)d_in[7];
    const float* bo = (const float*)d_in[8];
    float* out = (float*)d_out;

    char* ws = (char*)d_ws;
    size_t off = 0;
    auto alloc = [&](size_t bytes) -> char* {
        char* p = ws + off;
        off += (bytes + 255) & ~(size_t)255;
        return p;
    };

    unsigned short* hs_bf = (unsigned short*)alloc((size_t)MPAD * DMODEL * 2);
    unsigned short* wq_bf = (unsigned short*)alloc((size_t)DMODEL * DMODEL * 2);
    unsigned short* wk_bf = (unsigned short*)alloc((size_t)DMODEL * DMODEL * 2);
    unsigned short* wv_bf = (unsigned short*)alloc((size_t)DMODEL * DMODEL * 2);
    unsigned short* wo_bf = (unsigned short*)alloc((size_t)DMODEL * DMODEL * 2);
    unsigned short* qb    = (unsigned short*)alloc((size_t)NBH * SP * DP * 2);
    unsigned short* kb    = (unsigned short*)alloc((size_t)NBH * SP * DP * 2);
    unsigned short* vb    = (unsigned short*)alloc((size_t)NBH * SP * DP * 2);
    float* cos_t = (float*)alloc((size_t)SEQLEN * NFREQ * 4);
    float* sin_t = (float*)alloc((size_t)SEQLEN * NFREQ * 4);
    unsigned short* attn_bf = hs_bf;  // alias: hs_bf dead after QKV GEMMs

    if (off > ws_size) return;  // workspace too small: fail validation cleanly

    l4v_rope_table<<<dim3((SEQLEN * NFREQ + 255) / 256), dim3(256), 0, stream>>>(cos_t, sin_t);

    const int nhs = MROWS * DMODEL;          // 25,997,312 (divisible by 4)
    l4v_cvt_bf16<<<dim3(nhs / 4 / 256), dim3(256), 0, stream>>>(hs, hs_bf, nhs);
    const int nw = DMODEL * DMODEL;          // 1,982,464 (divisible by 4)
    l4v_cvt_bf16<<<dim3(nw / 4 / 256), dim3(256), 0, stream>>>(wq, wq_bf, nw);
    l4v_cvt_bf16<<<dim3(nw / 4 / 256), dim3(256), 0, stream>>>(wk, wk_bf, nw);
    l4v_cvt_bf16<<<dim3(nw / 4 / 256), dim3(256), 0, stream>>>(wv, wv_bf, nw);
    l4v_cvt_bf16<<<dim3(nw / 4 / 256), dim3(256), 0, stream>>>(wo, wo_bf, nw);

    dim3 ggrid(DMODEL / 128, MTILES);  // (11, 145)
    l4v_gemm128<<<ggrid, dim3(256), 0, stream>>>(hs_bf, wq_bf, bq, cos_t, sin_t, qb, nullptr, 0);
    l4v_gemm128<<<ggrid, dim3(256), 0, stream>>>(hs_bf, wk_bf, bk, cos_t, sin_t, kb, nullptr, 1);
    l4v_gemm128<<<ggrid, dim3(256), 0, stream>>>(hs_bf, wv_bf, bv, cos_t, sin_t, vb, nullptr, 2);

    l4v_attn<<<dim3(10, NBH), dim3(256), 0, stream>>>(qb, kb, vb, attn_bf);

    l4v_gemm128<<<ggrid, dim3(256), 0, stream>>>(attn_bf, wo_bf, bo, cos_t, sin_t, nullptr, out, 3);
}